// Round 1
// baseline (447.592 us; speedup 1.0000x reference)
//
#include <hip/hip_runtime.h>

#define DD 128
#define SH 7            // bucket = key >> SH ; keys per bucket = 128

typedef unsigned short u16;
typedef unsigned int   u32;
typedef __attribute__((ext_vector_type(8))) short bf16x8;
typedef __attribute__((ext_vector_type(4))) float f32x4;

__device__ __forceinline__ float blo(u32 u){ return __uint_as_float(u << 16); }
__device__ __forceinline__ float bhi(u32 u){ return __uint_as_float(u & 0xFFFF0000u); }
__device__ __forceinline__ u16 f2b(float f){
    u32 u = __float_as_uint(f);
    u32 r = u + 0x7FFFu + ((u >> 16) & 1u);
    return (u16)(r >> 16);
}

// ---------------- runtime environment detection ----------------
// flags[0] = 1 if h is int64 ; flags[1] = 1 if float inputs are f32
__global__ __launch_bounds__(256) void detect_kernel(const int* __restrict__ h32, int E,
                                                     const u32* __restrict__ xw,
                                                     int* __restrict__ flags)
{
    __shared__ int nzodd, sane;
    if (threadIdx.x == 0) { nzodd = 0; sane = 0; }
    __syncthreads();
    if (threadIdx.x < 64 && h32[2 * threadIdx.x + 1] != 0) atomicAdd(&nzodd, 1);
    for (int i = (int)threadIdx.x; i < 1024; i += 256) {
        u32 lo = xw[i] & 0xFFFFu;
        u32 ex = (lo >> 7) & 0xFFu;
        if (ex >= 100u && ex <= 140u) atomicAdd(&sane, 1);
    }
    __syncthreads();
    if (threadIdx.x == 0) {
        flags[0] = (nzodd == 0) ? 1 : 0;
        flags[1] = (sane < 700) ? 1 : 0;
    }
}

// ---------------- canonicalize weights (bf16) + biases (f32) ----------------
__global__ __launch_bounds__(256) void canon_kernel(
    const int* __restrict__ flags,
    const void* W0, const void* W1, const void* W2, const void* W3,
    const void* B0, const void* B1, const void* B2, const void* B3,
    u16* __restrict__ Wb, float* __restrict__ canonB)
{
    int idx = blockIdx.x * 256 + threadIdx.x;
    bool f32 = (flags[1] != 0);
    if (idx < 65536) {
        int m = idx >> 14, o = idx & 16383;
        const void* src;
        switch (m) { case 0: src = W0; break; case 1: src = W1; break;
                     case 2: src = W2; break; default: src = W3; }
        float v = f32 ? ((const float*)src)[o] : blo(((const u16*)src)[o]);
        Wb[idx] = f2b(v);
    } else {
        int j = idx - 65536; if (j >= 512) return;
        int m = j >> 7, o = j & 127;
        const void* src;
        switch (m) { case 0: src = B0; break; case 1: src = B1; break;
                     case 2: src = B2; break; default: src = B3; }
        canonB[j] = f32 ? ((const float*)src)[o] : blo(((const u16*)src)[o]);
    }
}

// ---------------- bucketed CSR build ----------------
__device__ __forceinline__ void load_edge(const int* __restrict__ h32, int e, int E,
                                          int idx64, int& v, int& u)
{
    if (idx64) { v = h32[2 * e]; u = h32[2 * E + 2 * e]; }
    else       { v = h32[e];     u = h32[E + e]; }
}

// K1: global bucket histogram (LDS-staged)
__global__ __launch_bounds__(256) void bucket_hist(const int* __restrict__ flags,
                                                   const int* __restrict__ h32,
                                                   int* __restrict__ bcnt,
                                                   int E, int NX, int NB)
{
    __shared__ int hist[1024];
    int tid = threadIdx.x;
    for (int i = tid; i < 1024; i += 256) hist[i] = 0;
    __syncthreads();
    int base = blockIdx.x * 4096;
    int idx64 = flags[0];
    for (int k = 0; k < 16; ++k) {
        int e = base + k * 256 + tid;
        if (e < E) {
            int v, u; load_edge(h32, e, E, idx64, v, u);
            atomicAdd(&hist[v >> SH], 1);
            atomicAdd(&hist[(NX + u) >> SH], 1);
        }
    }
    __syncthreads();
    for (int i = tid; i < NB; i += 256)
        if (hist[i]) atomicAdd(&bcnt[i], hist[i]);
}

// K2: scan bucket counts (NB <= 1024), init cursors, write off_all[NT]
__global__ __launch_bounds__(1024) void bucket_scan(const int* __restrict__ bcnt, int NB,
                                                    int* __restrict__ boff,
                                                    int* __restrict__ bcur,
                                                    int* __restrict__ off_all,
                                                    int NT, int total)
{
    __shared__ int s[1024];
    int t = threadIdx.x;
    int v = (t < NB) ? bcnt[t] : 0;
    s[t] = v;
    __syncthreads();
    for (int st = 1; st < 1024; st <<= 1) {
        int a = (t >= st) ? s[t - st] : 0;
        __syncthreads();
        s[t] += a;
        __syncthreads();
    }
    if (t < NB) { int excl = s[t] - v; boff[t] = excl; bcur[t] = excl; }
    if (t == 0) { boff[NB] = total; off_all[NT] = total; }
}

// K3: per-block counting sort into bucket-major record array (rec = (nbr<<7)|key_low7)
__global__ __launch_bounds__(256) void bucket_fill(const int* __restrict__ flags,
                                                   const int* __restrict__ h32,
                                                   int E, int NX, int NB,
                                                   int* __restrict__ bcur,
                                                   u32* __restrict__ recs)
{
    __shared__ u32 staged[8192];
    __shared__ int hist[1024], lstart[1024], gbase[1024], cur[1024];
    __shared__ int tscan[256];
    const int tid = threadIdx.x;
    const int base = blockIdx.x * 4096;
    const int idx64 = flags[0];

    for (int i = tid; i < 1024; i += 256) hist[i] = 0;
    __syncthreads();
    // pass 1: histogram
    for (int k = 0; k < 16; ++k) {
        int e = base + k * 256 + tid;
        if (e < E) {
            int v, u; load_edge(h32, e, E, idx64, v, u);
            atomicAdd(&hist[v >> SH], 1);
            atomicAdd(&hist[(NX + u) >> SH], 1);
        }
    }
    __syncthreads();
    // exclusive scan of hist -> lstart (4 buckets per thread + block scan)
    int b0 = tid * 4;
    int c0 = hist[b0], c1 = hist[b0 + 1], c2 = hist[b0 + 2], c3 = hist[b0 + 3];
    int sum = c0 + c1 + c2 + c3;
    tscan[tid] = sum;
    __syncthreads();
    for (int st = 1; st < 256; st <<= 1) {
        int a = (tid >= st) ? tscan[tid - st] : 0;
        __syncthreads();
        tscan[tid] += a;
        __syncthreads();
    }
    int run = tscan[tid] - sum;
    lstart[b0] = run; run += c0;
    lstart[b0 + 1] = run; run += c1;
    lstart[b0 + 2] = run; run += c2;
    lstart[b0 + 3] = run;
    __syncthreads();
    for (int i = tid; i < 1024; i += 256) cur[i] = lstart[i];
    __syncthreads();
    // pass 2: scatter records into staged (bucket-major within block)
    for (int k = 0; k < 16; ++k) {
        int e = base + k * 256 + tid;
        if (e < E) {
            int v, u; load_edge(h32, e, E, idx64, v, u);
            u32 r1 = ((u32)u << 7) | (u32)(v & 127);
            int p1 = atomicAdd(&cur[v >> SH], 1);
            staged[p1] = r1;
            int key2 = NX + u;
            u32 r2 = ((u32)v << 7) | (u32)(key2 & 127);
            int p2 = atomicAdd(&cur[key2 >> SH], 1);
            staged[p2] = r2;
        }
    }
    __syncthreads();
    // allocate global runs
    for (int i = tid; i < NB; i += 256) {
        int c = hist[i];
        gbase[i] = c ? atomicAdd(&bcur[i], c) : 0;
    }
    __syncthreads();
    // cooperative coalesced flush (binary search bucket per record)
    int nrec = tscan[255];
    for (int i = tid; i < nrec; i += 256) {
        u32 r = staged[i];
        int lo = 0, hi = NB - 1;
        while (lo < hi) {
            int mid = (lo + hi + 1) >> 1;
            if (lstart[mid] <= i) lo = mid; else hi = mid - 1;
        }
        recs[gbase[lo] + (i - lstart[lo])] = r;
    }
}

// K4: one block per bucket — local 128-key sort IN PLACE, emit off_all
// NOTE: records now KEEP their low-7 key bits: rec = (nbr<<7)|key_low7.
// The fused phase derives neighbor = rec>>7 and tile-local row = rec&15.
__global__ __launch_bounds__(256) void bucket_to_csr(const int* __restrict__ boff,
                                                     int NB, int NT,
                                                     u32* __restrict__ recs,
                                                     int* __restrict__ off_all)
{
    __shared__ u32 buf[8192];
    __shared__ int hist[128], lofs[128], cur[128];
    const int b = blockIdx.x;
    const int tid = threadIdx.x;
    const int s = boff[b];
    const int n = boff[b + 1] - s;

    if (tid < 128) hist[tid] = 0;
    __syncthreads();
    for (int i = tid; i < n; i += 256) {
        u32 r = recs[s + i];
        buf[i] = r;
        atomicAdd(&hist[r & 127], 1);
    }
    __syncthreads();
    if (tid < 128) lofs[tid] = hist[tid];
    __syncthreads();
    for (int st = 1; st < 128; st <<= 1) {
        int a = 0;
        if (tid < 128 && tid >= st) a = lofs[tid - st];
        __syncthreads();
        if (tid < 128) lofs[tid] += a;
        __syncthreads();
    }
    if (tid < 128) {
        int excl = lofs[tid] - hist[tid];
        int key = (b << SH) + tid;
        if (key < NT) off_all[key] = s + excl;
        cur[tid] = excl;
    }
    __syncthreads();
    for (int i = tid; i < n; i += 256) {
        u32 r = buf[i];
        int p = atomicAdd(&cur[r & 127], 1);
        recs[s + p] = r;               // keep full record
    }
}

// ---------------- fused phase: edge-parallel gather + double MFMA + epilogue ----
// Block handles 16 output rows [r0, r0+16). CSR is globally key-sorted, so the
// tile's edges are the contiguous range [off[r0], off[r0+16]). Edge groups walk
// contiguous sub-ranges; each lane owns a fixed feature slice and accumulates
// same-row runs in registers, flushing to an LDS f32 tile on row change
// (branch is uniform per edge-group -> no divergence). Tile-local row = rec&15
// (valid: r0, NX are multiples of 16).
__global__ __launch_bounds__(256) void fused_mfma_phase(
    const int* __restrict__ flags,
    const void* __restrict__ gtab, size_t goff,
    const void* __restrict__ stab,
    const u16* __restrict__ Wg, const u16* __restrict__ Ws,
    const float* __restrict__ bg, const float* __restrict__ bs,
    const int* __restrict__ off, const u32* __restrict__ recs,
    void* __restrict__ out, size_t ooff, int M)
{
    const bool F32 = (flags[1] != 0);
    const int tid = threadIdx.x;
    const int r0 = blockIdx.x * 16;

    __shared__ float sAgg[16][132];   // +4 pad: fn stride 132 -> 2-4 way banks
    __shared__ float sSelf[16][132];
    __shared__ float sdeg[16];
    __shared__ int   soff[17];

    {
        float* z = &sAgg[0][0];
        for (int i = tid; i < 16 * 132; i += 256) z[i] = 0.f;
    }
    if (tid < 17) {
        int rr = r0 + tid; if (rr > M) rr = M;
        soff[tid] = off[rr];
    }
    __syncthreads();

    if (tid < 16) sdeg[tid] = (float)(soff[tid + 1] - soff[tid]);
    const int eS = soff[0];
    const int eE = soff[16];
    const int nE = eE - eS;

    if (F32) {
        const float* gt = (const float*)gtab + goff;
        const int s = tid & 31, g = tid >> 5;          // 8 groups x 32 lanes
        const int L = (nE + 7) >> 3;
        int e  = eS + g * L;
        int e1 = e + L; if (e1 > eE) e1 = eE;
        if (e < e1) {
            u32 rc = recs[e];
            int lr = (int)(rc & 15u);
            float4 v = *(const float4*)(gt + (size_t)(rc >> 7) * DD + s * 4);
            float a0 = v.x, a1 = v.y, a2 = v.z, a3 = v.w;
            for (++e; e < e1; ++e) {
                u32 rc2 = recs[e];
                float4 w4 = *(const float4*)(gt + (size_t)(rc2 >> 7) * DD + s * 4);
                int lr2 = (int)(rc2 & 15u);
                if (lr2 != lr) {                       // uniform across group
                    atomicAdd(&sAgg[lr][s * 4 + 0], a0);
                    atomicAdd(&sAgg[lr][s * 4 + 1], a1);
                    atomicAdd(&sAgg[lr][s * 4 + 2], a2);
                    atomicAdd(&sAgg[lr][s * 4 + 3], a3);
                    lr = lr2; a0 = w4.x; a1 = w4.y; a2 = w4.z; a3 = w4.w;
                } else {
                    a0 += w4.x; a1 += w4.y; a2 += w4.z; a3 += w4.w;
                }
            }
            atomicAdd(&sAgg[lr][s * 4 + 0], a0);
            atomicAdd(&sAgg[lr][s * 4 + 1], a1);
            atomicAdd(&sAgg[lr][s * 4 + 2], a2);
            atomicAdd(&sAgg[lr][s * 4 + 3], a3);
        }
        // self staging: 2 passes x (8 rows x 32 slices)
        const float* st = (const float*)stab;
#pragma unroll
        for (int p2 = 0; p2 < 2; ++p2) {
            int row = (tid >> 5) + p2 * 8;
            int rr = r0 + row;
            float4 v = make_float4(0.f, 0.f, 0.f, 0.f);
            if (rr < M) v = *(const float4*)(st + (size_t)rr * DD + s * 4);
            *(float4*)&sSelf[row][s * 4] = v;
        }
    } else {
        const u16* gt = (const u16*)gtab + goff;
        const int s = tid & 15, g = tid >> 4;          // 16 groups x 16 lanes
        const int L = (nE + 15) >> 4;
        int e  = eS + g * L;
        int e1 = e + L; if (e1 > eE) e1 = eE;
        if (e < e1) {
            u32 rc = recs[e];
            int lr = (int)(rc & 15u);
            uint4 pv = *(const uint4*)(gt + (size_t)(rc >> 7) * DD + s * 8);
            float a0 = blo(pv.x), a1 = bhi(pv.x), a2 = blo(pv.y), a3 = bhi(pv.y);
            float a4 = blo(pv.z), a5 = bhi(pv.z), a6 = blo(pv.w), a7 = bhi(pv.w);
            for (++e; e < e1; ++e) {
                u32 rc2 = recs[e];
                uint4 qv = *(const uint4*)(gt + (size_t)(rc2 >> 7) * DD + s * 8);
                int lr2 = (int)(rc2 & 15u);
                if (lr2 != lr) {
                    atomicAdd(&sAgg[lr][s * 8 + 0], a0);
                    atomicAdd(&sAgg[lr][s * 8 + 1], a1);
                    atomicAdd(&sAgg[lr][s * 8 + 2], a2);
                    atomicAdd(&sAgg[lr][s * 8 + 3], a3);
                    atomicAdd(&sAgg[lr][s * 8 + 4], a4);
                    atomicAdd(&sAgg[lr][s * 8 + 5], a5);
                    atomicAdd(&sAgg[lr][s * 8 + 6], a6);
                    atomicAdd(&sAgg[lr][s * 8 + 7], a7);
                    lr = lr2;
                    a0 = blo(qv.x); a1 = bhi(qv.x); a2 = blo(qv.y); a3 = bhi(qv.y);
                    a4 = blo(qv.z); a5 = bhi(qv.z); a6 = blo(qv.w); a7 = bhi(qv.w);
                } else {
                    a0 += blo(qv.x); a1 += bhi(qv.x); a2 += blo(qv.y); a3 += bhi(qv.y);
                    a4 += blo(qv.z); a5 += bhi(qv.z); a6 += blo(qv.w); a7 += bhi(qv.w);
                }
            }
            atomicAdd(&sAgg[lr][s * 8 + 0], a0);
            atomicAdd(&sAgg[lr][s * 8 + 1], a1);
            atomicAdd(&sAgg[lr][s * 8 + 2], a2);
            atomicAdd(&sAgg[lr][s * 8 + 3], a3);
            atomicAdd(&sAgg[lr][s * 8 + 4], a4);
            atomicAdd(&sAgg[lr][s * 8 + 5], a5);
            atomicAdd(&sAgg[lr][s * 8 + 6], a6);
            atomicAdd(&sAgg[lr][s * 8 + 7], a7);
        }
        // self staging: 16 rows x 16 slices (one pass)
        const u16* st = (const u16*)stab;
        {
            int row = tid >> 4;
            int rr = r0 + row;
            float* d = &sSelf[row][s * 8];
            if (rr < M) {
                uint4 pv = *(const uint4*)(st + (size_t)rr * DD + s * 8);
                d[0] = blo(pv.x); d[1] = bhi(pv.x); d[2] = blo(pv.y); d[3] = bhi(pv.y);
                d[4] = blo(pv.z); d[5] = bhi(pv.z); d[6] = blo(pv.w); d[7] = bhi(pv.w);
            } else {
#pragma unroll
                for (int j = 0; j < 8; ++j) d[j] = 0.f;
            }
        }
    }
    __syncthreads();

    // ---- MFMA stage (unchanged layout; fragments packed from f32 LDS) ----
    const int lane = tid & 63, wid = tid >> 6;
    const int fn = lane & 15, q = lane >> 4, qk = q * 8;

    bf16x8 Bg[2][4], Bs[2][4];
#pragma unroll
    for (int t = 0; t < 2; ++t) {
        int n = 32 * wid + 16 * t + fn;
#pragma unroll
        for (int c = 0; c < 4; ++c) {
            Bg[t][c] = *(const bf16x8*)(Wg + (size_t)n * DD + 32 * c + qk);
            Bs[t][c] = *(const bf16x8*)(Ws + (size_t)n * DD + 32 * c + qk);
        }
    }

    f32x4 accA[2], accS[2];
#pragma unroll
    for (int t = 0; t < 2; ++t)
#pragma unroll
        for (int i = 0; i < 4; ++i) { accA[t][i] = 0.f; accS[t][i] = 0.f; }

#pragma unroll
    for (int c = 0; c < 4; ++c) {
        const float* pa = &sAgg[fn][32 * c + qk];
        const float* ps = &sSelf[fn][32 * c + qk];
        union { bf16x8 v; u16 h[8]; } Ua, Us;
#pragma unroll
        for (int j = 0; j < 8; ++j) { Ua.h[j] = f2b(pa[j]); Us.h[j] = f2b(ps[j]); }
#pragma unroll
        for (int t = 0; t < 2; ++t) {
            accA[t] = __builtin_amdgcn_mfma_f32_16x16x32_bf16(Ua.v, Bg[t][c], accA[t], 0, 0, 0);
            accS[t] = __builtin_amdgcn_mfma_f32_16x16x32_bf16(Us.v, Bs[t][c], accS[t], 0, 0, 0);
        }
    }

#pragma unroll
    for (int t = 0; t < 2; ++t) {
        int col = 32 * wid + 16 * t + fn;
        float bsv = bs[col], bgv = bg[col];
#pragma unroll
        for (int i = 0; i < 4; ++i) {
            int rr = q * 4 + i;
            int rw = r0 + rr;
            if (rw >= M) continue;
            float S = accS[t][i] + bsv;
            float A = accA[t][i] + sdeg[rr] * bgv;
            float res = S * (1.f + A);
            if (F32) ((float*)out)[ooff + (size_t)rw * DD + col] = res;
            else     ((u16*)out)[ooff + (size_t)rw * DD + col] = f2b(res);
        }
    }
}

static inline size_t alignup(size_t v){ return (v + 255) & ~(size_t)255; }

extern "C" void kernel_launch(void* const* d_in, const int* in_sizes, int n_in,
                              void* d_out, int out_size, void* d_ws, size_t ws_size,
                              hipStream_t stream)
{
    const int NX = in_sizes[0] / DD;    // 100000
    const int NW = in_sizes[1] / DD;    // 25000
    const int E  = in_sizes[10] / 2;    // 800000
    const int NT = NX + NW;
    const int NB = (NT + ((1 << SH) - 1)) >> SH;   // 977 (<= 1024 required)

    const void* x   = d_in[0];
    const void* w   = d_in[1];
    const int*  h32 = (const int*)d_in[10];

    // workspace (~7.05 MB)
    char* ws = (char*)d_ws;
    size_t o = 0;
    int*   flags   = (int*)(ws + o); o = alignup(o + sizeof(int) * 8);
    int*   off_all = (int*)(ws + o); o = alignup(o + sizeof(int) * (size_t)(NT + 1));
    int*   boff    = (int*)(ws + o); o = alignup(o + sizeof(int) * (size_t)(NB + 1));
    int*   bcnt    = (int*)(ws + o); o = alignup(o + sizeof(int) * (size_t)NB);
    int*   bcur    = (int*)(ws + o); o = alignup(o + sizeof(int) * (size_t)NB);
    u16*   Wb      = (u16*)(ws + o); o = alignup(o + sizeof(u16) * 65536);
    float* canonB  = (float*)(ws + o); o = alignup(o + sizeof(float) * 512);
    u32*   cv_all  = (u32*)(ws + o); o = alignup(o + sizeof(u32) * (size_t)2 * E);

    detect_kernel<<<1, 256, 0, stream>>>(h32, E, (const u32*)x, flags);

    canon_kernel<<<(66048 + 255) / 256, 256, 0, stream>>>(
        flags, d_in[4], d_in[2], d_in[6], d_in[8],   // Ww1, Wx1, Wx2, Ww2
               d_in[5], d_in[3], d_in[7], d_in[9],   // bw1, bx1, bx2, bw2
        Wb, canonB);

    hipMemsetAsync(bcnt, 0, sizeof(int) * (size_t)NB, stream);

    int eb4k = (E + 4095) / 4096;
    bucket_hist<<<eb4k, 256, 0, stream>>>(flags, h32, bcnt, E, NX, NB);
    bucket_scan<<<1, 1024, 0, stream>>>(bcnt, NB, boff, bcur, off_all, NT, 2 * E);
    bucket_fill<<<eb4k, 256, 0, stream>>>(flags, h32, E, NX, NB, bcur, cv_all);
    bucket_to_csr<<<NB, 256, 0, stream>>>(boff, NB, NT, cv_all, off_all);

    // out layout: [w_new (NW*DD) | x_new (NX*DD)] in detected dtype
    size_t xoff = (size_t)NW * DD;

    // Phase 1 (MPToVertex): x_new = (x@Wx1^T+bx1) * (1 + segsum_v(w)@Ww1^T + deg_v*bw1)
    fused_mfma_phase<<<(NX + 15) / 16, 256, 0, stream>>>(
        flags, w, 0, x,
        Wb + 0 * 16384, Wb + 1 * 16384, canonB + 0, canonB + 128,
        off_all, cv_all, d_out, xoff, NX);

    // Phase 2 (MPToEdge): w_new = (w@Ww2^T+bw2) * (1 + segsum_e(x_new)@Wx2^T + deg_e*bx2)
    fused_mfma_phase<<<(NW + 15) / 16, 256, 0, stream>>>(
        flags, d_out, xoff, w,
        Wb + 2 * 16384, Wb + 3 * 16384, canonB + 256, canonB + 384,
        off_all + NX, cv_all, d_out, 0, NW);
}

// Round 2
// 372.284 us; speedup vs baseline: 1.2023x; 1.2023x over previous
//
#include <hip/hip_runtime.h>

#define DD 128
#define SH 7            // bucket = key >> SH ; keys per bucket = 128

typedef unsigned short u16;
typedef unsigned int   u32;
typedef __attribute__((ext_vector_type(8))) short bf16x8;
typedef __attribute__((ext_vector_type(4))) float f32x4;

__device__ __forceinline__ float blo(u32 u){ return __uint_as_float(u << 16); }
__device__ __forceinline__ float bhi(u32 u){ return __uint_as_float(u & 0xFFFF0000u); }
__device__ __forceinline__ u16 f2b(float f){
    u32 u = __float_as_uint(f);
    u32 r = u + 0x7FFFu + ((u >> 16) & 1u);
    return (u16)(r >> 16);
}

// ---------------- runtime environment detection ----------------
// flags[0] = 1 if h is int64 ; flags[1] = 1 if float inputs are f32
__global__ __launch_bounds__(256) void detect_kernel(const int* __restrict__ h32, int E,
                                                     const u32* __restrict__ xw,
                                                     int* __restrict__ flags)
{
    __shared__ int nzodd, sane;
    if (threadIdx.x == 0) { nzodd = 0; sane = 0; }
    __syncthreads();
    if (threadIdx.x < 64 && h32[2 * threadIdx.x + 1] != 0) atomicAdd(&nzodd, 1);
    for (int i = (int)threadIdx.x; i < 1024; i += 256) {
        u32 lo = xw[i] & 0xFFFFu;
        u32 ex = (lo >> 7) & 0xFFu;
        if (ex >= 100u && ex <= 140u) atomicAdd(&sane, 1);
    }
    __syncthreads();
    if (threadIdx.x == 0) {
        flags[0] = (nzodd == 0) ? 1 : 0;
        flags[1] = (sane < 700) ? 1 : 0;
    }
}

// ---------------- canonicalize weights (bf16) + biases (f32) ----------------
__global__ __launch_bounds__(256) void canon_kernel(
    const int* __restrict__ flags,
    const void* W0, const void* W1, const void* W2, const void* W3,
    const void* B0, const void* B1, const void* B2, const void* B3,
    u16* __restrict__ Wb, float* __restrict__ canonB)
{
    int idx = blockIdx.x * 256 + threadIdx.x;
    bool f32 = (flags[1] != 0);
    if (idx < 65536) {
        int m = idx >> 14, o = idx & 16383;
        const void* src;
        switch (m) { case 0: src = W0; break; case 1: src = W1; break;
                     case 2: src = W2; break; default: src = W3; }
        float v = f32 ? ((const float*)src)[o] : blo(((const u16*)src)[o]);
        Wb[idx] = f2b(v);
    } else {
        int j = idx - 65536; if (j >= 512) return;
        int m = j >> 7, o = j & 127;
        const void* src;
        switch (m) { case 0: src = B0; break; case 1: src = B1; break;
                     case 2: src = B2; break; default: src = B3; }
        canonB[j] = f32 ? ((const float*)src)[o] : blo(((const u16*)src)[o]);
    }
}

// ---------------- bf16 gather-table prep: wb = bf16(w) ----------------
__global__ __launch_bounds__(256) void prep_w(const int* __restrict__ flags,
                                              const void* __restrict__ w,
                                              u16* __restrict__ wb, int n)
{
    int t8 = (blockIdx.x * 256 + threadIdx.x) * 8;
    if (t8 >= n) return;
    if (flags[1] != 0) {
        const float* s = (const float*)w + t8;
        float4 a = *(const float4*)s;
        float4 b = *(const float4*)(s + 4);
        uint4 o;
        o.x = ((u32)f2b(a.y) << 16) | (u32)f2b(a.x);
        o.y = ((u32)f2b(a.w) << 16) | (u32)f2b(a.z);
        o.z = ((u32)f2b(b.y) << 16) | (u32)f2b(b.x);
        o.w = ((u32)f2b(b.w) << 16) | (u32)f2b(b.z);
        *(uint4*)(wb + t8) = o;
    } else {
        *(uint4*)(wb + t8) = *(const uint4*)((const u16*)w + t8);
    }
}

// ---------------- bucketed CSR build ----------------
__device__ __forceinline__ void load_edge(const int* __restrict__ h32, int e, int E,
                                          int idx64, int& v, int& u)
{
    if (idx64) { v = h32[2 * e]; u = h32[2 * E + 2 * e]; }
    else       { v = h32[e];     u = h32[E + e]; }
}

// K1: global bucket histogram (LDS-staged)
__global__ __launch_bounds__(256) void bucket_hist(const int* __restrict__ flags,
                                                   const int* __restrict__ h32,
                                                   int* __restrict__ bcnt,
                                                   int E, int NX, int NB)
{
    __shared__ int hist[1024];
    int tid = threadIdx.x;
    for (int i = tid; i < 1024; i += 256) hist[i] = 0;
    __syncthreads();
    int base = blockIdx.x * 4096;
    int idx64 = flags[0];
    for (int k = 0; k < 16; ++k) {
        int e = base + k * 256 + tid;
        if (e < E) {
            int v, u; load_edge(h32, e, E, idx64, v, u);
            atomicAdd(&hist[v >> SH], 1);
            atomicAdd(&hist[(NX + u) >> SH], 1);
        }
    }
    __syncthreads();
    for (int i = tid; i < NB; i += 256)
        if (hist[i]) atomicAdd(&bcnt[i], hist[i]);
}

// K2: scan bucket counts (NB <= 1024), init cursors, write off_all[NT]
__global__ __launch_bounds__(1024) void bucket_scan(const int* __restrict__ bcnt, int NB,
                                                    int* __restrict__ boff,
                                                    int* __restrict__ bcur,
                                                    int* __restrict__ off_all,
                                                    int NT, int total)
{
    __shared__ int s[1024];
    int t = threadIdx.x;
    int v = (t < NB) ? bcnt[t] : 0;
    s[t] = v;
    __syncthreads();
    for (int st = 1; st < 1024; st <<= 1) {
        int a = (t >= st) ? s[t - st] : 0;
        __syncthreads();
        s[t] += a;
        __syncthreads();
    }
    if (t < NB) { int excl = s[t] - v; boff[t] = excl; bcur[t] = excl; }
    if (t == 0) { boff[NB] = total; off_all[NT] = total; }
}

// K3: per-block counting sort into bucket-major record array (rec = (nbr<<7)|key_low7)
__global__ __launch_bounds__(256) void bucket_fill(const int* __restrict__ flags,
                                                   const int* __restrict__ h32,
                                                   int E, int NX, int NB,
                                                   int* __restrict__ bcur,
                                                   u32* __restrict__ recs)
{
    __shared__ u32 staged[8192];
    __shared__ int hist[1024], lstart[1024], gbase[1024], cur[1024];
    __shared__ int tscan[256];
    const int tid = threadIdx.x;
    const int base = blockIdx.x * 4096;
    const int idx64 = flags[0];

    for (int i = tid; i < 1024; i += 256) hist[i] = 0;
    __syncthreads();
    // pass 1: histogram
    for (int k = 0; k < 16; ++k) {
        int e = base + k * 256 + tid;
        if (e < E) {
            int v, u; load_edge(h32, e, E, idx64, v, u);
            atomicAdd(&hist[v >> SH], 1);
            atomicAdd(&hist[(NX + u) >> SH], 1);
        }
    }
    __syncthreads();
    // exclusive scan of hist -> lstart (4 buckets per thread + block scan)
    int b0 = tid * 4;
    int c0 = hist[b0], c1 = hist[b0 + 1], c2 = hist[b0 + 2], c3 = hist[b0 + 3];
    int sum = c0 + c1 + c2 + c3;
    tscan[tid] = sum;
    __syncthreads();
    for (int st = 1; st < 256; st <<= 1) {
        int a = (tid >= st) ? tscan[tid - st] : 0;
        __syncthreads();
        tscan[tid] += a;
        __syncthreads();
    }
    int run = tscan[tid] - sum;
    lstart[b0] = run; run += c0;
    lstart[b0 + 1] = run; run += c1;
    lstart[b0 + 2] = run; run += c2;
    lstart[b0 + 3] = run;
    __syncthreads();
    for (int i = tid; i < 1024; i += 256) cur[i] = lstart[i];
    __syncthreads();
    // pass 2: scatter records into staged (bucket-major within block)
    for (int k = 0; k < 16; ++k) {
        int e = base + k * 256 + tid;
        if (e < E) {
            int v, u; load_edge(h32, e, E, idx64, v, u);
            u32 r1 = ((u32)u << 7) | (u32)(v & 127);
            int p1 = atomicAdd(&cur[v >> SH], 1);
            staged[p1] = r1;
            int key2 = NX + u;
            u32 r2 = ((u32)v << 7) | (u32)(key2 & 127);
            int p2 = atomicAdd(&cur[key2 >> SH], 1);
            staged[p2] = r2;
        }
    }
    __syncthreads();
    // allocate global runs
    for (int i = tid; i < NB; i += 256) {
        int c = hist[i];
        gbase[i] = c ? atomicAdd(&bcur[i], c) : 0;
    }
    __syncthreads();
    // cooperative coalesced flush (binary search bucket per record)
    int nrec = tscan[255];
    for (int i = tid; i < nrec; i += 256) {
        u32 r = staged[i];
        int lo = 0, hi = NB - 1;
        while (lo < hi) {
            int mid = (lo + hi + 1) >> 1;
            if (lstart[mid] <= i) lo = mid; else hi = mid - 1;
        }
        recs[gbase[lo] + (i - lstart[lo])] = r;
    }
}

// K4: one block per bucket — local 128-key sort IN PLACE, emit off_all + cv
__global__ __launch_bounds__(256) void bucket_to_csr(const int* __restrict__ boff,
                                                     int NB, int NT,
                                                     u32* __restrict__ recs,
                                                     int* __restrict__ off_all)
{
    __shared__ u32 buf[8192];
    __shared__ int hist[128], lofs[128], cur[128];
    const int b = blockIdx.x;
    const int tid = threadIdx.x;
    const int s = boff[b];
    const int n = boff[b + 1] - s;

    if (tid < 128) hist[tid] = 0;
    __syncthreads();
    for (int i = tid; i < n; i += 256) {
        u32 r = recs[s + i];
        buf[i] = r;
        atomicAdd(&hist[r & 127], 1);
    }
    __syncthreads();
    if (tid < 128) lofs[tid] = hist[tid];
    __syncthreads();
    for (int st = 1; st < 128; st <<= 1) {
        int a = 0;
        if (tid < 128 && tid >= st) a = lofs[tid - st];
        __syncthreads();
        if (tid < 128) lofs[tid] += a;
        __syncthreads();
    }
    if (tid < 128) {
        int excl = lofs[tid] - hist[tid];
        int key = (b << SH) + tid;
        if (key < NT) off_all[key] = s + excl;
        cur[tid] = excl;
    }
    __syncthreads();
    for (int i = tid; i < n; i += 256) {
        u32 r = buf[i];
        int p = atomicAdd(&cur[r & 127], 1);
        recs[s + p] = r >> 7;      // final cv value = neighbor id
    }
}

// ---------------- fused phase: lane-parallel gather + double MFMA + epilogue ----
// Gather source priority: tb (prepared bf16 table) > dtyped gtab fallback.
// ROWS rows per block (16 for phase 1, 8 for phase 2); mirror = optional bf16
// copy of the output (feeds next phase's gather table).
__global__ __launch_bounds__(256) void fused_mfma_phase(
    const int* __restrict__ flags,
    const u16* __restrict__ tb,
    const void* __restrict__ gtab, size_t goff,
    const void* __restrict__ stab,
    const u16* __restrict__ Wg, const u16* __restrict__ Ws,
    const float* __restrict__ bg, const float* __restrict__ bs,
    const int* __restrict__ off, const int* __restrict__ cv,
    void* __restrict__ out, size_t ooff, u16* __restrict__ mirror,
    int M, int ROWS)
{
    const bool F32 = (flags[1] != 0);
    const int lane = threadIdx.x & 63;
    const int wid  = threadIdx.x >> 6;
    const int fn   = lane & 15;
    const int q    = lane >> 4;
    const int feat = wid * 32 + q * 8;
    const int r0   = blockIdx.x * ROWS;

    __shared__ u16  sA[16][136];
    __shared__ u16  sS[16][136];
    __shared__ float sdeg[16];

    float a0=0.f,a1=0.f,a2=0.f,a3=0.f,a4=0.f,a5=0.f,a6=0.f,a7=0.f;
    float s0=0.f,s1=0.f,s2=0.f,s3=0.f,s4=0.f,s5=0.f,s6=0.f,s7=0.f;
    int deg = 0;

    const int r = r0 + fn;
    if (fn < ROWS && r < M) {
        int start = off[r], end = off[r + 1];
        deg = end - start;
        const u16* gt16 = tb ? tb : (F32 ? (const u16*)0 : (const u16*)gtab + goff);
        if (gt16) {
            int e = start;
            for (; e + 3 < end; e += 4) {
                int i0 = cv[e], i1 = cv[e + 1], i2 = cv[e + 2], i3 = cv[e + 3];
                uint4 p0 = *(const uint4*)(gt16 + (size_t)i0 * DD + feat);
                uint4 p1 = *(const uint4*)(gt16 + (size_t)i1 * DD + feat);
                uint4 p2 = *(const uint4*)(gt16 + (size_t)i2 * DD + feat);
                uint4 p3 = *(const uint4*)(gt16 + (size_t)i3 * DD + feat);
                a0 += blo(p0.x) + blo(p1.x) + blo(p2.x) + blo(p3.x);
                a1 += bhi(p0.x) + bhi(p1.x) + bhi(p2.x) + bhi(p3.x);
                a2 += blo(p0.y) + blo(p1.y) + blo(p2.y) + blo(p3.y);
                a3 += bhi(p0.y) + bhi(p1.y) + bhi(p2.y) + bhi(p3.y);
                a4 += blo(p0.z) + blo(p1.z) + blo(p2.z) + blo(p3.z);
                a5 += bhi(p0.z) + bhi(p1.z) + bhi(p2.z) + bhi(p3.z);
                a6 += blo(p0.w) + blo(p1.w) + blo(p2.w) + blo(p3.w);
                a7 += bhi(p0.w) + bhi(p1.w) + bhi(p2.w) + bhi(p3.w);
            }
            for (; e < end; ++e) {
                uint4 pa = *(const uint4*)(gt16 + (size_t)cv[e] * DD + feat);
                a0 += blo(pa.x); a1 += bhi(pa.x); a2 += blo(pa.y); a3 += bhi(pa.y);
                a4 += blo(pa.z); a5 += bhi(pa.z); a6 += blo(pa.w); a7 += bhi(pa.w);
            }
        } else {
            const float* gt = (const float*)gtab + goff;
            int e = start;
            for (; e + 1 < end; e += 2) {
                int i0 = cv[e], i1 = cv[e + 1];
                float4 va = *(const float4*)(gt + (size_t)i0 * DD + feat);
                float4 vb = *(const float4*)(gt + (size_t)i0 * DD + feat + 4);
                float4 vc = *(const float4*)(gt + (size_t)i1 * DD + feat);
                float4 vd = *(const float4*)(gt + (size_t)i1 * DD + feat + 4);
                a0 += va.x + vc.x; a1 += va.y + vc.y; a2 += va.z + vc.z; a3 += va.w + vc.w;
                a4 += vb.x + vd.x; a5 += vb.y + vd.y; a6 += vb.z + vd.z; a7 += vb.w + vd.w;
            }
            if (e < end) {
                int i0 = cv[e];
                float4 va = *(const float4*)(gt + (size_t)i0 * DD + feat);
                float4 vb = *(const float4*)(gt + (size_t)i0 * DD + feat + 4);
                a0 += va.x; a1 += va.y; a2 += va.z; a3 += va.w;
                a4 += vb.x; a5 += vb.y; a6 += vb.z; a7 += vb.w;
            }
        }
        if (F32) {
            const float* sp = (const float*)stab + (size_t)r * DD + feat;
            float4 sa = *(const float4*)sp;
            float4 sb = *(const float4*)(sp + 4);
            s0=sa.x; s1=sa.y; s2=sa.z; s3=sa.w; s4=sb.x; s5=sb.y; s6=sb.z; s7=sb.w;
        } else {
            uint4 sp = *(const uint4*)((const u16*)stab + (size_t)r * DD + feat);
            s0=blo(sp.x); s1=bhi(sp.x); s2=blo(sp.y); s3=bhi(sp.y);
            s4=blo(sp.z); s5=bhi(sp.z); s6=blo(sp.w); s7=bhi(sp.w);
        }
    }

    uint4 pk;
    pk.x = ((u32)f2b(a1) << 16) | (u32)f2b(a0);
    pk.y = ((u32)f2b(a3) << 16) | (u32)f2b(a2);
    pk.z = ((u32)f2b(a5) << 16) | (u32)f2b(a4);
    pk.w = ((u32)f2b(a7) << 16) | (u32)f2b(a6);
    *(uint4*)&sA[fn][feat] = pk;
    pk.x = ((u32)f2b(s1) << 16) | (u32)f2b(s0);
    pk.y = ((u32)f2b(s3) << 16) | (u32)f2b(s2);
    pk.z = ((u32)f2b(s5) << 16) | (u32)f2b(s4);
    pk.w = ((u32)f2b(s7) << 16) | (u32)f2b(s6);
    *(uint4*)&sS[fn][feat] = pk;
    if (threadIdx.x < 16) sdeg[threadIdx.x] = 0.f;
    if (wid == 0 && q == 0) sdeg[fn] = (float)deg;
    __syncthreads();

    const int qk = q * 8;
    bf16x8 Bg[2][4], Bs[2][4];
#pragma unroll
    for (int t = 0; t < 2; ++t) {
        int n = 32 * wid + 16 * t + fn;
#pragma unroll
        for (int c = 0; c < 4; ++c) {
            Bg[t][c] = *(const bf16x8*)(Wg + (size_t)n * DD + 32 * c + qk);
            Bs[t][c] = *(const bf16x8*)(Ws + (size_t)n * DD + 32 * c + qk);
        }
    }

    f32x4 accA[2], accS[2];
#pragma unroll
    for (int t = 0; t < 2; ++t)
#pragma unroll
        for (int i = 0; i < 4; ++i) { accA[t][i] = 0.f; accS[t][i] = 0.f; }

#pragma unroll
    for (int c = 0; c < 4; ++c) {
        bf16x8 Ag = *(const bf16x8*)&sA[fn][32 * c + qk];
        bf16x8 As = *(const bf16x8*)&sS[fn][32 * c + qk];
#pragma unroll
        for (int t = 0; t < 2; ++t) {
            accA[t] = __builtin_amdgcn_mfma_f32_16x16x32_bf16(Ag, Bg[t][c], accA[t], 0, 0, 0);
            accS[t] = __builtin_amdgcn_mfma_f32_16x16x32_bf16(As, Bs[t][c], accS[t], 0, 0, 0);
        }
    }

#pragma unroll
    for (int t = 0; t < 2; ++t) {
        int col = 32 * wid + 16 * t + fn;
        float bsv = bs[col], bgv = bg[col];
#pragma unroll
        for (int i = 0; i < 4; ++i) {
            int rr = q * 4 + i;
            if (rr >= ROWS) continue;
            int rw = r0 + rr;
            if (rw >= M) continue;
            float S = accS[t][i] + bsv;
            float A = accA[t][i] + sdeg[rr] * bgv;
            float res = S * (1.f + A);
            u16 rb = f2b(res);
            if (F32) ((float*)out)[ooff + (size_t)rw * DD + col] = res;
            else     ((u16*)out)[ooff + (size_t)rw * DD + col] = rb;
            if (mirror) mirror[(size_t)rw * DD + col] = rb;
        }
    }
}

static inline size_t alignup(size_t v){ return (v + 255) & ~(size_t)255; }

extern "C" void kernel_launch(void* const* d_in, const int* in_sizes, int n_in,
                              void* d_out, int out_size, void* d_ws, size_t ws_size,
                              hipStream_t stream)
{
    const int NX = in_sizes[0] / DD;    // 100000
    const int NW = in_sizes[1] / DD;    // 25000
    const int E  = in_sizes[10] / 2;    // 800000
    const int NT = NX + NW;
    const int NB = (NT + ((1 << SH) - 1)) >> SH;   // 977 (<= 1024 required)

    const void* x   = d_in[0];
    const void* w   = d_in[1];
    const int*  h32 = (const int*)d_in[10];

    // workspace
    char* ws = (char*)d_ws;
    size_t o = 0;
    int*   flags   = (int*)(ws + o); o = alignup(o + sizeof(int) * 8);
    int*   off_all = (int*)(ws + o); o = alignup(o + sizeof(int) * (size_t)(NT + 1));
    int*   boff    = (int*)(ws + o); o = alignup(o + sizeof(int) * (size_t)(NB + 1));
    int*   bcnt    = (int*)(ws + o); o = alignup(o + sizeof(int) * (size_t)NB);
    int*   bcur    = (int*)(ws + o); o = alignup(o + sizeof(int) * (size_t)NB);
    u16*   Wb      = (u16*)(ws + o); o = alignup(o + sizeof(u16) * 65536);
    float* canonB  = (float*)(ws + o); o = alignup(o + sizeof(float) * 512);
    u32*   cv_all  = (u32*)(ws + o); o = alignup(o + sizeof(u32) * (size_t)2 * E);
    // bf16 gather tables (optional, guarded by ws_size)
    u16*   wb      = (u16*)(ws + o); size_t o_wb = o; o = alignup(o + sizeof(u16) * (size_t)NW * DD);
    u16*   xb      = (u16*)(ws + o); o = alignup(o + sizeof(u16) * (size_t)NX * DD);
    const bool big = (o <= ws_size);
    if (!big) { wb = nullptr; xb = nullptr; (void)o_wb; }

    detect_kernel<<<1, 256, 0, stream>>>(h32, E, (const u32*)x, flags);

    canon_kernel<<<(66048 + 255) / 256, 256, 0, stream>>>(
        flags, d_in[4], d_in[2], d_in[6], d_in[8],   // Ww1, Wx1, Wx2, Ww2
               d_in[5], d_in[3], d_in[7], d_in[9],   // bw1, bx1, bx2, bw2
        Wb, canonB);

    hipMemsetAsync(bcnt, 0, sizeof(int) * (size_t)NB, stream);

    int eb4k = (E + 4095) / 4096;
    bucket_hist<<<eb4k, 256, 0, stream>>>(flags, h32, bcnt, E, NX, NB);
    bucket_scan<<<1, 1024, 0, stream>>>(bcnt, NB, boff, bcur, off_all, NT, 2 * E);
    bucket_fill<<<eb4k, 256, 0, stream>>>(flags, h32, E, NX, NB, bcur, cv_all);
    bucket_to_csr<<<NB, 256, 0, stream>>>(boff, NB, NT, cv_all, off_all);

    if (wb) {
        int nW16 = NW * DD;
        prep_w<<<(nW16 / 8 + 255) / 256, 256, 0, stream>>>(flags, w, wb, nW16);
    }

    // out layout: [w_new (NW*DD) | x_new (NX*DD)] in detected dtype
    size_t xoff = (size_t)NW * DD;

    // Phase 1 (MPToVertex): x_new = (x@Wx1^T+bx1) * (1 + segsum_v(w)@Ww1^T + deg_v*bw1)
    fused_mfma_phase<<<(NX + 15) / 16, 256, 0, stream>>>(
        flags, wb, w, 0, x,
        Wb + 0 * 16384, Wb + 1 * 16384, canonB + 0, canonB + 128,
        off_all, (const int*)cv_all, d_out, xoff, xb, NX, 16);

    // Phase 2 (MPToEdge): w_new = (w@Ww2^T+bw2) * (1 + segsum_e(x_new)@Wx2^T + deg_e*bx2)
    fused_mfma_phase<<<(NW + 7) / 8, 256, 0, stream>>>(
        flags, xb, d_out, xoff, w,
        Wb + 2 * 16384, Wb + 3 * 16384, canonB + 256, canonB + 384,
        off_all + NX, (const int*)cv_all, d_out, 0, nullptr, NW, 8);
}

// Round 3
// 363.791 us; speedup vs baseline: 1.2304x; 1.0233x over previous
//
#include <hip/hip_runtime.h>

#define DD 128
#define SH 7            // bucket = key >> SH ; keys per bucket = 128

typedef unsigned short u16;
typedef unsigned int   u32;
typedef __attribute__((ext_vector_type(8))) short bf16x8;
typedef __attribute__((ext_vector_type(4))) float f32x4;

__device__ __forceinline__ float blo(u32 u){ return __uint_as_float(u << 16); }
__device__ __forceinline__ float bhi(u32 u){ return __uint_as_float(u & 0xFFFF0000u); }
__device__ __forceinline__ u16 f2b(float f){
    u32 u = __float_as_uint(f);
    u32 r = u + 0x7FFFu + ((u >> 16) & 1u);
    return (u16)(r >> 16);
}

// ---------------- runtime environment detection ----------------
// flags[0] = 1 if h is int64 ; flags[1] = 1 if float inputs are f32
__global__ __launch_bounds__(256) void detect_kernel(const int* __restrict__ h32, int E,
                                                     const u32* __restrict__ xw,
                                                     int* __restrict__ flags)
{
    __shared__ int nzodd, sane;
    if (threadIdx.x == 0) { nzodd = 0; sane = 0; }
    __syncthreads();
    if (threadIdx.x < 64 && h32[2 * threadIdx.x + 1] != 0) atomicAdd(&nzodd, 1);
    for (int i = (int)threadIdx.x; i < 1024; i += 256) {
        u32 lo = xw[i] & 0xFFFFu;
        u32 ex = (lo >> 7) & 0xFFu;
        if (ex >= 100u && ex <= 140u) atomicAdd(&sane, 1);
    }
    __syncthreads();
    if (threadIdx.x == 0) {
        flags[0] = (nzodd == 0) ? 1 : 0;
        flags[1] = (sane < 700) ? 1 : 0;
    }
}

// ---------------- canonicalize weights (bf16) + biases (f32) ----------------
__global__ __launch_bounds__(256) void canon_kernel(
    const int* __restrict__ flags,
    const void* W0, const void* W1, const void* W2, const void* W3,
    const void* B0, const void* B1, const void* B2, const void* B3,
    u16* __restrict__ Wb, float* __restrict__ canonB)
{
    int idx = blockIdx.x * 256 + threadIdx.x;
    bool f32 = (flags[1] != 0);
    if (idx < 65536) {
        int m = idx >> 14, o = idx & 16383;
        const void* src;
        switch (m) { case 0: src = W0; break; case 1: src = W1; break;
                     case 2: src = W2; break; default: src = W3; }
        float v = f32 ? ((const float*)src)[o] : blo(((const u16*)src)[o]);
        Wb[idx] = f2b(v);
    } else {
        int j = idx - 65536; if (j >= 512) return;
        int m = j >> 7, o = j & 127;
        const void* src;
        switch (m) { case 0: src = B0; break; case 1: src = B1; break;
                     case 2: src = B2; break; default: src = B3; }
        canonB[j] = f32 ? ((const float*)src)[o] : blo(((const u16*)src)[o]);
    }
}

// ---------------- bf16 gather-table prep: wb = bf16(w) ----------------
__global__ __launch_bounds__(256) void prep_w(const int* __restrict__ flags,
                                              const void* __restrict__ w,
                                              u16* __restrict__ wb, int n)
{
    int t8 = (blockIdx.x * 256 + threadIdx.x) * 8;
    if (t8 >= n) return;
    if (flags[1] != 0) {
        const float* s = (const float*)w + t8;
        float4 a = *(const float4*)s;
        float4 b = *(const float4*)(s + 4);
        uint4 o;
        o.x = ((u32)f2b(a.y) << 16) | (u32)f2b(a.x);
        o.y = ((u32)f2b(a.w) << 16) | (u32)f2b(a.z);
        o.z = ((u32)f2b(b.y) << 16) | (u32)f2b(b.x);
        o.w = ((u32)f2b(b.w) << 16) | (u32)f2b(b.z);
        *(uint4*)(wb + t8) = o;
    } else {
        *(uint4*)(wb + t8) = *(const uint4*)((const u16*)w + t8);
    }
}

// ---------------- bucketed CSR build ----------------
__device__ __forceinline__ void load_edge(const int* __restrict__ h32, int e, int E,
                                          int idx64, int& v, int& u)
{
    if (idx64) { v = h32[2 * e]; u = h32[2 * E + 2 * e]; }
    else       { v = h32[e];     u = h32[E + e]; }
}

// K1: global bucket histogram (LDS-staged)
__global__ __launch_bounds__(256) void bucket_hist(const int* __restrict__ flags,
                                                   const int* __restrict__ h32,
                                                   int* __restrict__ bcnt,
                                                   int E, int NX, int NB)
{
    __shared__ int hist[1024];
    int tid = threadIdx.x;
    for (int i = tid; i < 1024; i += 256) hist[i] = 0;
    __syncthreads();
    int base = blockIdx.x * 4096;
    int idx64 = flags[0];
    for (int k = 0; k < 16; ++k) {
        int e = base + k * 256 + tid;
        if (e < E) {
            int v, u; load_edge(h32, e, E, idx64, v, u);
            atomicAdd(&hist[v >> SH], 1);
            atomicAdd(&hist[(NX + u) >> SH], 1);
        }
    }
    __syncthreads();
    for (int i = tid; i < NB; i += 256)
        if (hist[i]) atomicAdd(&bcnt[i], hist[i]);
}

// K2: scan bucket counts (NB <= 1024), init cursors, write off_all[NT]
__global__ __launch_bounds__(1024) void bucket_scan(const int* __restrict__ bcnt, int NB,
                                                    int* __restrict__ boff,
                                                    int* __restrict__ bcur,
                                                    int* __restrict__ off_all,
                                                    int NT, int total)
{
    __shared__ int s[1024];
    int t = threadIdx.x;
    int v = (t < NB) ? bcnt[t] : 0;
    s[t] = v;
    __syncthreads();
    for (int st = 1; st < 1024; st <<= 1) {
        int a = (t >= st) ? s[t - st] : 0;
        __syncthreads();
        s[t] += a;
        __syncthreads();
    }
    if (t < NB) { int excl = s[t] - v; boff[t] = excl; bcur[t] = excl; }
    if (t == 0) { boff[NB] = total; off_all[NT] = total; }
}

// K3: per-block counting sort into bucket-major record array (rec = (nbr<<7)|key_low7)
__global__ __launch_bounds__(256) void bucket_fill(const int* __restrict__ flags,
                                                   const int* __restrict__ h32,
                                                   int E, int NX, int NB,
                                                   int* __restrict__ bcur,
                                                   u32* __restrict__ recs)
{
    __shared__ u32 staged[8192];
    __shared__ int hist[1024], lstart[1024], gbase[1024], cur[1024];
    __shared__ int tscan[256];
    const int tid = threadIdx.x;
    const int base = blockIdx.x * 4096;
    const int idx64 = flags[0];

    for (int i = tid; i < 1024; i += 256) hist[i] = 0;
    __syncthreads();
    // pass 1: histogram
    for (int k = 0; k < 16; ++k) {
        int e = base + k * 256 + tid;
        if (e < E) {
            int v, u; load_edge(h32, e, E, idx64, v, u);
            atomicAdd(&hist[v >> SH], 1);
            atomicAdd(&hist[(NX + u) >> SH], 1);
        }
    }
    __syncthreads();
    // exclusive scan of hist -> lstart (4 buckets per thread + block scan)
    int b0 = tid * 4;
    int c0 = hist[b0], c1 = hist[b0 + 1], c2 = hist[b0 + 2], c3 = hist[b0 + 3];
    int sum = c0 + c1 + c2 + c3;
    tscan[tid] = sum;
    __syncthreads();
    for (int st = 1; st < 256; st <<= 1) {
        int a = (tid >= st) ? tscan[tid - st] : 0;
        __syncthreads();
        tscan[tid] += a;
        __syncthreads();
    }
    int run = tscan[tid] - sum;
    lstart[b0] = run; run += c0;
    lstart[b0 + 1] = run; run += c1;
    lstart[b0 + 2] = run; run += c2;
    lstart[b0 + 3] = run;
    __syncthreads();
    for (int i = tid; i < 1024; i += 256) cur[i] = lstart[i];
    __syncthreads();
    // pass 2: scatter records into staged (bucket-major within block)
    for (int k = 0; k < 16; ++k) {
        int e = base + k * 256 + tid;
        if (e < E) {
            int v, u; load_edge(h32, e, E, idx64, v, u);
            u32 r1 = ((u32)u << 7) | (u32)(v & 127);
            int p1 = atomicAdd(&cur[v >> SH], 1);
            staged[p1] = r1;
            int key2 = NX + u;
            u32 r2 = ((u32)v << 7) | (u32)(key2 & 127);
            int p2 = atomicAdd(&cur[key2 >> SH], 1);
            staged[p2] = r2;
        }
    }
    __syncthreads();
    // allocate global runs
    for (int i = tid; i < NB; i += 256) {
        int c = hist[i];
        gbase[i] = c ? atomicAdd(&bcur[i], c) : 0;
    }
    __syncthreads();
    // cooperative coalesced flush (binary search bucket per record)
    int nrec = tscan[255];
    for (int i = tid; i < nrec; i += 256) {
        u32 r = staged[i];
        int lo = 0, hi = NB - 1;
        while (lo < hi) {
            int mid = (lo + hi + 1) >> 1;
            if (lstart[mid] <= i) lo = mid; else hi = mid - 1;
        }
        recs[gbase[lo] + (i - lstart[lo])] = r;
    }
}

// K4: one block per bucket — local 128-key sort IN PLACE, emit off_all + cv
__global__ __launch_bounds__(256) void bucket_to_csr(const int* __restrict__ boff,
                                                     int NB, int NT,
                                                     u32* __restrict__ recs,
                                                     int* __restrict__ off_all)
{
    __shared__ u32 buf[8192];
    __shared__ int hist[128], lofs[128], cur[128];
    const int b = blockIdx.x;
    const int tid = threadIdx.x;
    const int s = boff[b];
    const int n = boff[b + 1] - s;

    if (tid < 128) hist[tid] = 0;
    __syncthreads();
    for (int i = tid; i < n; i += 256) {
        u32 r = recs[s + i];
        buf[i] = r;
        atomicAdd(&hist[r & 127], 1);
    }
    __syncthreads();
    if (tid < 128) lofs[tid] = hist[tid];
    __syncthreads();
    for (int st = 1; st < 128; st <<= 1) {
        int a = 0;
        if (tid < 128 && tid >= st) a = lofs[tid - st];
        __syncthreads();
        if (tid < 128) lofs[tid] += a;
        __syncthreads();
    }
    if (tid < 128) {
        int excl = lofs[tid] - hist[tid];
        int key = (b << SH) + tid;
        if (key < NT) off_all[key] = s + excl;
        cur[tid] = excl;
    }
    __syncthreads();
    for (int i = tid; i < n; i += 256) {
        u32 r = buf[i];
        int p = atomicAdd(&cur[r & 127], 1);
        recs[s + p] = r >> 7;      // final cv value = neighbor id
    }
}

// ---------------- fused phase: deep-pipelined gather + double MFMA + epilogue ----
// ROWS=16: one lane-group per (row, feat-slice).  ROWS=8: two edge-groups per
// row (grp = fn>>3) combined via shfl_xor(8) — all 64 lanes gather.
// tb path: zero-padded rounds of 8 unconditional loads (index clamped to zero
// row ZR) -> 8 loads in flight per lane, no serial remainder.
template<int ROWS>
__global__ __launch_bounds__(256) void fused_mfma_phase(
    const int* __restrict__ flags,
    const u16* __restrict__ tb, int ZR,
    const void* __restrict__ gtab, size_t goff,
    const void* __restrict__ stab,
    const u16* __restrict__ Wg, const u16* __restrict__ Ws,
    const float* __restrict__ bg, const float* __restrict__ bs,
    const int* __restrict__ off, const int* __restrict__ cv,
    void* __restrict__ out, size_t ooff, u16* __restrict__ mirror,
    int M)
{
    constexpr int NGRP = 16 / ROWS;          // 1 or 2
    const bool F32 = (flags[1] != 0);
    const int lane = threadIdx.x & 63;
    const int wid  = threadIdx.x >> 6;
    const int fn   = lane & 15;
    const int q    = lane >> 4;
    const int feat = wid * 32 + q * 8;
    const int row  = fn & (ROWS - 1);
    const int grp  = fn / ROWS;              // 0 when NGRP==1
    const int r0   = blockIdx.x * ROWS;
    const int r    = r0 + row;

    __shared__ u16  sA[16][136];
    __shared__ u16  sS[16][136];
    __shared__ float sdeg[16];

    float a0=0.f,a1=0.f,a2=0.f,a3=0.f,a4=0.f,a5=0.f,a6=0.f,a7=0.f;
    float s0=0.f,s1=0.f,s2=0.f,s3=0.f,s4=0.f,s5=0.f,s6=0.f,s7=0.f;
    int deg = 0, start = 0, end = 0;

    if (r < M) { start = off[r]; end = off[r + 1]; deg = end - start; }

    if (tb) {
        // ---- deep-pipelined bf16 gather with zero-row padding ----
        int len = (deg + NGRP - 1) / NGRP;
        int gs = start + grp * len;
        int ge = gs + len; if (ge > end) ge = end;
        int rounds = (ge > gs) ? ((ge - gs + 7) >> 3) : 0;
        for (int rd = 0; rd < rounds; ++rd) {
            int ix[8];
#pragma unroll
            for (int j = 0; j < 8; ++j)
                ix[j] = (gs + j < ge) ? cv[gs + j] : ZR;
            uint4 p[8];
#pragma unroll
            for (int j = 0; j < 8; ++j)
                p[j] = *(const uint4*)(tb + (size_t)((u32)ix[j] * DD) + feat);
#pragma unroll
            for (int j = 0; j < 8; ++j) {
                a0 += blo(p[j].x); a1 += bhi(p[j].x);
                a2 += blo(p[j].y); a3 += bhi(p[j].y);
                a4 += blo(p[j].z); a5 += bhi(p[j].z);
                a6 += blo(p[j].w); a7 += bhi(p[j].w);
            }
            gs += 8;
        }
    } else if (!F32) {
        if (grp == 0 && r < M) {
            const u16* gt16 = (const u16*)gtab + goff;
            int e = start;
            for (; e + 3 < end; e += 4) {
                int i0 = cv[e], i1 = cv[e + 1], i2 = cv[e + 2], i3 = cv[e + 3];
                uint4 p0 = *(const uint4*)(gt16 + (size_t)i0 * DD + feat);
                uint4 p1 = *(const uint4*)(gt16 + (size_t)i1 * DD + feat);
                uint4 p2 = *(const uint4*)(gt16 + (size_t)i2 * DD + feat);
                uint4 p3 = *(const uint4*)(gt16 + (size_t)i3 * DD + feat);
                a0 += blo(p0.x) + blo(p1.x) + blo(p2.x) + blo(p3.x);
                a1 += bhi(p0.x) + bhi(p1.x) + bhi(p2.x) + bhi(p3.x);
                a2 += blo(p0.y) + blo(p1.y) + blo(p2.y) + blo(p3.y);
                a3 += bhi(p0.y) + bhi(p1.y) + bhi(p2.y) + bhi(p3.y);
                a4 += blo(p0.z) + blo(p1.z) + blo(p2.z) + blo(p3.z);
                a5 += bhi(p0.z) + bhi(p1.z) + bhi(p2.z) + bhi(p3.z);
                a6 += blo(p0.w) + blo(p1.w) + blo(p2.w) + blo(p3.w);
                a7 += bhi(p0.w) + bhi(p1.w) + bhi(p2.w) + bhi(p3.w);
            }
            for (; e < end; ++e) {
                uint4 pa = *(const uint4*)(gt16 + (size_t)cv[e] * DD + feat);
                a0 += blo(pa.x); a1 += bhi(pa.x); a2 += blo(pa.y); a3 += bhi(pa.y);
                a4 += blo(pa.z); a5 += bhi(pa.z); a6 += blo(pa.w); a7 += bhi(pa.w);
            }
        }
    } else {
        if (grp == 0 && r < M) {
            const float* gt = (const float*)gtab + goff;
            int e = start;
            for (; e + 1 < end; e += 2) {
                int i0 = cv[e], i1 = cv[e + 1];
                float4 va = *(const float4*)(gt + (size_t)i0 * DD + feat);
                float4 vb = *(const float4*)(gt + (size_t)i0 * DD + feat + 4);
                float4 vc = *(const float4*)(gt + (size_t)i1 * DD + feat);
                float4 vd = *(const float4*)(gt + (size_t)i1 * DD + feat + 4);
                a0 += va.x + vc.x; a1 += va.y + vc.y; a2 += va.z + vc.z; a3 += va.w + vc.w;
                a4 += vb.x + vd.x; a5 += vb.y + vd.y; a6 += vb.z + vd.z; a7 += vb.w + vd.w;
            }
            if (e < end) {
                int i0 = cv[e];
                float4 va = *(const float4*)(gt + (size_t)i0 * DD + feat);
                float4 vb = *(const float4*)(gt + (size_t)i0 * DD + feat + 4);
                a0 += va.x; a1 += va.y; a2 += va.z; a3 += va.w;
                a4 += vb.x; a5 += vb.y; a6 += vb.z; a7 += vb.w;
            }
        }
    }

    // combine the two edge-groups (ROWS==8 only)
    if constexpr (NGRP == 2) {
        a0 += __shfl_xor(a0, 8); a1 += __shfl_xor(a1, 8);
        a2 += __shfl_xor(a2, 8); a3 += __shfl_xor(a3, 8);
        a4 += __shfl_xor(a4, 8); a5 += __shfl_xor(a5, 8);
        a6 += __shfl_xor(a6, 8); a7 += __shfl_xor(a7, 8);
    }

    // self row
    if (r < M) {
        if (F32) {
            const float* sp = (const float*)stab + (size_t)r * DD + feat;
            float4 sa = *(const float4*)sp;
            float4 sb = *(const float4*)(sp + 4);
            s0=sa.x; s1=sa.y; s2=sa.z; s3=sa.w; s4=sb.x; s5=sb.y; s6=sb.z; s7=sb.w;
        } else {
            uint4 sp = *(const uint4*)((const u16*)stab + (size_t)r * DD + feat);
            s0=blo(sp.x); s1=bhi(sp.x); s2=blo(sp.y); s3=bhi(sp.y);
            s4=blo(sp.z); s5=bhi(sp.z); s6=blo(sp.w); s7=bhi(sp.w);
        }
    }

    uint4 pk;
    pk.x = ((u32)f2b(a1) << 16) | (u32)f2b(a0);
    pk.y = ((u32)f2b(a3) << 16) | (u32)f2b(a2);
    pk.z = ((u32)f2b(a5) << 16) | (u32)f2b(a4);
    pk.w = ((u32)f2b(a7) << 16) | (u32)f2b(a6);
    *(uint4*)&sA[fn][feat] = pk;
    pk.x = ((u32)f2b(s1) << 16) | (u32)f2b(s0);
    pk.y = ((u32)f2b(s3) << 16) | (u32)f2b(s2);
    pk.z = ((u32)f2b(s5) << 16) | (u32)f2b(s4);
    pk.w = ((u32)f2b(s7) << 16) | (u32)f2b(s6);
    *(uint4*)&sS[fn][feat] = pk;
    if (threadIdx.x < 16) sdeg[threadIdx.x] = 0.f;
    if (wid == 0 && q == 0 && grp == 0) sdeg[row] = (float)deg;
    __syncthreads();

    const int qk = q * 8;
    bf16x8 Bg[2][4], Bs[2][4];
#pragma unroll
    for (int t = 0; t < 2; ++t) {
        int n = 32 * wid + 16 * t + fn;
#pragma unroll
        for (int c = 0; c < 4; ++c) {
            Bg[t][c] = *(const bf16x8*)(Wg + (size_t)n * DD + 32 * c + qk);
            Bs[t][c] = *(const bf16x8*)(Ws + (size_t)n * DD + 32 * c + qk);
        }
    }

    f32x4 accA[2], accS[2];
#pragma unroll
    for (int t = 0; t < 2; ++t)
#pragma unroll
        for (int i = 0; i < 4; ++i) { accA[t][i] = 0.f; accS[t][i] = 0.f; }

#pragma unroll
    for (int c = 0; c < 4; ++c) {
        bf16x8 Ag = *(const bf16x8*)&sA[fn][32 * c + qk];
        bf16x8 As = *(const bf16x8*)&sS[fn][32 * c + qk];
#pragma unroll
        for (int t = 0; t < 2; ++t) {
            accA[t] = __builtin_amdgcn_mfma_f32_16x16x32_bf16(Ag, Bg[t][c], accA[t], 0, 0, 0);
            accS[t] = __builtin_amdgcn_mfma_f32_16x16x32_bf16(As, Bs[t][c], accS[t], 0, 0, 0);
        }
    }

#pragma unroll
    for (int t = 0; t < 2; ++t) {
        int col = 32 * wid + 16 * t + fn;
        float bsv = bs[col], bgv = bg[col];
#pragma unroll
        for (int i = 0; i < 4; ++i) {
            int rr = q * 4 + i;
            if (rr >= ROWS) continue;
            int rw = r0 + rr;
            if (rw >= M) continue;
            float S = accS[t][i] + bsv;
            float A = accA[t][i] + sdeg[rr] * bgv;
            float res = S * (1.f + A);
            u16 rb = f2b(res);
            if (F32) ((float*)out)[ooff + (size_t)rw * DD + col] = res;
            else     ((u16*)out)[ooff + (size_t)rw * DD + col] = rb;
            if (mirror) mirror[(size_t)rw * DD + col] = rb;
        }
    }
}

static inline size_t alignup(size_t v){ return (v + 255) & ~(size_t)255; }

extern "C" void kernel_launch(void* const* d_in, const int* in_sizes, int n_in,
                              void* d_out, int out_size, void* d_ws, size_t ws_size,
                              hipStream_t stream)
{
    const int NX = in_sizes[0] / DD;    // 100000
    const int NW = in_sizes[1] / DD;    // 25000
    const int E  = in_sizes[10] / 2;    // 800000
    const int NT = NX + NW;
    const int NB = (NT + ((1 << SH) - 1)) >> SH;   // 977 (<= 1024 required)

    const void* x   = d_in[0];
    const void* w   = d_in[1];
    const int*  h32 = (const int*)d_in[10];

    // workspace
    char* ws = (char*)d_ws;
    size_t o = 0;
    int*   flags   = (int*)(ws + o); o = alignup(o + sizeof(int) * 8);
    int*   off_all = (int*)(ws + o); o = alignup(o + sizeof(int) * (size_t)(NT + 1));
    int*   boff    = (int*)(ws + o); o = alignup(o + sizeof(int) * (size_t)(NB + 1));
    int*   bcnt    = (int*)(ws + o); o = alignup(o + sizeof(int) * (size_t)NB);
    int*   bcur    = (int*)(ws + o); o = alignup(o + sizeof(int) * (size_t)NB);
    u16*   Wb      = (u16*)(ws + o); o = alignup(o + sizeof(u16) * 65536);
    float* canonB  = (float*)(ws + o); o = alignup(o + sizeof(float) * 512);
    u32*   cv_all  = (u32*)(ws + o); o = alignup(o + sizeof(u32) * ((size_t)2 * E + 8));
    // bf16 gather tables with one extra zero row each (guarded by ws_size)
    u16*   wb      = (u16*)(ws + o); o = alignup(o + sizeof(u16) * (size_t)(NW + 1) * DD);
    u16*   xb      = (u16*)(ws + o); o = alignup(o + sizeof(u16) * (size_t)(NX + 1) * DD);
    const bool big = (o <= ws_size);
    if (!big) { wb = nullptr; xb = nullptr; }

    detect_kernel<<<1, 256, 0, stream>>>(h32, E, (const u32*)x, flags);

    canon_kernel<<<(66048 + 255) / 256, 256, 0, stream>>>(
        flags, d_in[4], d_in[2], d_in[6], d_in[8],   // Ww1, Wx1, Wx2, Ww2
               d_in[5], d_in[3], d_in[7], d_in[9],   // bw1, bx1, bx2, bw2
        Wb, canonB);

    hipMemsetAsync(bcnt, 0, sizeof(int) * (size_t)NB, stream);

    int eb4k = (E + 4095) / 4096;
    bucket_hist<<<eb4k, 256, 0, stream>>>(flags, h32, bcnt, E, NX, NB);
    bucket_scan<<<1, 1024, 0, stream>>>(bcnt, NB, boff, bcur, off_all, NT, 2 * E);
    bucket_fill<<<eb4k, 256, 0, stream>>>(flags, h32, E, NX, NB, bcur, cv_all);
    bucket_to_csr<<<NB, 256, 0, stream>>>(boff, NB, NT, cv_all, off_all);

    if (wb) {
        int nW16 = NW * DD;
        prep_w<<<(nW16 / 8 + 255) / 256, 256, 0, stream>>>(flags, w, wb, nW16);
        hipMemsetAsync(wb + (size_t)NW * DD, 0, sizeof(u16) * DD, stream);
        hipMemsetAsync(xb + (size_t)NX * DD, 0, sizeof(u16) * DD, stream);
    }

    // out layout: [w_new (NW*DD) | x_new (NX*DD)] in detected dtype
    size_t xoff = (size_t)NW * DD;

    // Phase 1 (MPToVertex): x_new = (x@Wx1^T+bx1) * (1 + segsum_v(w)@Ww1^T + deg_v*bw1)
    fused_mfma_phase<16><<<(NX + 15) / 16, 256, 0, stream>>>(
        flags, wb, NW, w, 0, x,
        Wb + 0 * 16384, Wb + 1 * 16384, canonB + 0, canonB + 128,
        off_all, (const int*)cv_all, d_out, xoff, xb, NX);

    // Phase 2 (MPToEdge): w_new = (w@Ww2^T+bw2) * (1 + segsum_e(x_new)@Wx2^T + deg_e*bx2)
    fused_mfma_phase<8><<<(NW + 7) / 8, 256, 0, stream>>>(
        flags, xb, NX, d_out, xoff, w,
        Wb + 2 * 16384, Wb + 3 * 16384, canonB + 256, canonB + 384,
        off_all + NX, (const int*)cv_all, d_out, 0, nullptr, NW);
}